// Round 1
// baseline (12104.637 us; speedup 1.0000x reference)
//
#include <hip/hip_runtime.h>

// Problem constants (from reference)
#define BATCH 8
#define TSEQ 8
#define CIN_X 3
#define HH 64
#define WW 64
#define PROJ 32
#define CDIM 32
#define HID 64
#define PT 10  // process_time = T + NUM_NODE - 1

#define TILE 16
#define CI_CHUNK 16
#define CO_CHUNK 16

// ---------------------------------------------------------------------------
// Weight repack: w[co][ci][ky][kx] -> wr[(ci*9 + k)*Cout + co]
// so inner-loop weight reads are contiguous in co (uniform across the block).
// ---------------------------------------------------------------------------
__global__ void repack_k(const float* __restrict__ w, float* __restrict__ wr,
                         int Cout, int Cin) {
    int i = blockIdx.x * 256 + threadIdx.x;
    int total = Cout * Cin * 9;
    if (i >= total) return;
    int co = i / (Cin * 9);
    int r  = i - co * (Cin * 9);   // ci*9 + k
    wr[r * Cout + co] = w[i];
}

// ---------------------------------------------------------------------------
// Generic 3x3 same-pad conv, NCHW.
// MODE 0: plain conv of inA (cA channels).
// MODE 1: gates conv: input = concat(inA[cA], inB[cB]); sigmoid -> out (Cout=2*HID)
// MODE 2: cand conv: input = concat(inA[cA], r*inB) with r = gates[ch 0..HID);
//         epilogue: h_new = z*h + (1-z)*tanh(acc), z = gates[ch HID..2*HID)
// aStride: batch stride (elements) of inA (to handle x[:,t] slicing).
// ---------------------------------------------------------------------------
template <int MODE>
__global__ __launch_bounds__(256) void conv3x3_k(
    const float* __restrict__ inA, int cA, long aStride,
    const float* __restrict__ inB, int cB,
    const float* __restrict__ gates,
    const float* __restrict__ wr, const float* __restrict__ bias,
    float* __restrict__ out, int Cout)
{
    const int tid = threadIdx.x;
    const int tx = tid & (TILE - 1), ty = tid >> 4;
    const int x0 = blockIdx.x * TILE, y0 = blockIdx.y * TILE;
    const int nCo = Cout / CO_CHUNK;
    const int b   = blockIdx.z / nCo;
    const int co0 = (blockIdx.z % nCo) * CO_CHUNK;
    const int Cin = cA + cB;

    __shared__ float s_in[CI_CHUNK][TILE + 2][TILE + 2];

    float acc[CO_CHUNK];
#pragma unroll
    for (int i = 0; i < CO_CHUNK; ++i) acc[i] = bias[co0 + i];

    for (int c0 = 0; c0 < Cin; c0 += CI_CHUNK) {
        const int cn = (Cin - c0 < CI_CHUNK) ? (Cin - c0) : CI_CHUNK;
        __syncthreads();
        // --- stage input tile (with 1-pixel halo, zero padding) ---
        for (int idx = tid; idx < cn * (TILE + 2) * (TILE + 2); idx += 256) {
            int c  = idx / ((TILE + 2) * (TILE + 2));
            int r  = idx - c * (TILE + 2) * (TILE + 2);
            int yy = r / (TILE + 2);
            int xx = r - yy * (TILE + 2);
            int gy = y0 + yy - 1, gx = x0 + xx - 1;
            float v = 0.f;
            if (gy >= 0 && gy < HH && gx >= 0 && gx < WW) {
                int cg = c0 + c;
                if (MODE == 0 || cg < cA) {
                    v = inA[(long)b * aStride + ((long)cg * HH + gy) * WW + gx];
                } else {
                    int ch = cg - cA;
                    float hv = inB[(((long)b * cB + ch) * HH + gy) * WW + gx];
                    if (MODE == 2) {
                        float rv = gates[(((long)b * (2 * HID) + ch) * HH + gy) * WW + gx];
                        hv *= rv;
                    }
                    v = hv;
                }
            }
            s_in[c][yy][xx] = v;
        }
        __syncthreads();
        // --- accumulate ---
        for (int c = 0; c < cn; ++c) {
#pragma unroll
            for (int k = 0; k < 9; ++k) {
                const int ky = k / 3, kx = k % 3;
                const float v = s_in[c][ty + ky][tx + kx];
                const float* wrp = &wr[((long)(c0 + c) * 9 + k) * Cout + co0];
#pragma unroll
                for (int i = 0; i < CO_CHUNK; ++i) acc[i] += v * wrp[i];
            }
        }
    }

    const int gy = y0 + ty, gx = x0 + tx;
    if (MODE == 0) {
#pragma unroll
        for (int i = 0; i < CO_CHUNK; ++i)
            out[(((long)b * Cout + co0 + i) * HH + gy) * WW + gx] = acc[i];
    } else if (MODE == 1) {
#pragma unroll
        for (int i = 0; i < CO_CHUNK; ++i)
            out[(((long)b * Cout + co0 + i) * HH + gy) * WW + gx] =
                1.0f / (1.0f + expf(-acc[i]));
    } else {
#pragma unroll
        for (int i = 0; i < CO_CHUNK; ++i) {
            int ch = co0 + i;
            float z  = gates[(((long)b * (2 * HID) + HID + ch) * HH + gy) * WW + gx];
            float hv = inB[(((long)b * HID + ch) * HH + gy) * WW + gx];
            float cd = tanhf(acc[i]);
            out[(((long)b * HID + ch) * HH + gy) * WW + gx] = z * hv + (1.0f - z) * cd;
        }
    }
}

__global__ void copy_k(const float* __restrict__ src, float* __restrict__ dst, int n) {
    int i = blockIdx.x * 256 + threadIdx.x;
    if (i < n) dst[i] = src[i];
}

// ---------------------------------------------------------------------------
// Host orchestration
// ---------------------------------------------------------------------------
static inline void launch_conv(int mode, const float* inA, int cA, long aStride,
                               const float* inB, int cB, const float* gates,
                               const float* wr, const float* bias,
                               float* out, int Cout, hipStream_t s) {
    dim3 grid(WW / TILE, HH / TILE, BATCH * (Cout / CO_CHUNK));
    dim3 block(256);
    if (mode == 0)
        conv3x3_k<0><<<grid, block, 0, s>>>(inA, cA, aStride, inB, cB, gates, wr, bias, out, Cout);
    else if (mode == 1)
        conv3x3_k<1><<<grid, block, 0, s>>>(inA, cA, aStride, inB, cB, gates, wr, bias, out, Cout);
    else
        conv3x3_k<2><<<grid, block, 0, s>>>(inA, cA, aStride, inB, cB, gates, wr, bias, out, Cout);
}

static inline void launch_repack(const float* w, float* wr, int Cout, int Cin, hipStream_t s) {
    int total = Cout * Cin * 9;
    repack_k<<<(total + 255) / 256, 256, 0, s>>>(w, wr, Cout, Cin);
}

extern "C" void kernel_launch(void* const* d_in, const int* in_sizes, int n_in,
                              void* d_out, int out_size, void* d_ws, size_t ws_size,
                              hipStream_t stream) {
    const float* x    = (const float*)d_in[0];
    const float* Win0 = (const float*)d_in[1];
    const float* bin0 = (const float*)d_in[2];
    const float* We10 = (const float*)d_in[3];
    const float* be10 = (const float*)d_in[4];
    const float* We21 = (const float*)d_in[5];
    const float* be21 = (const float*)d_in[6];
    const float* Wint[3] = {(const float*)d_in[7],  (const float*)d_in[13], (const float*)d_in[19]};
    const float* bint[3] = {(const float*)d_in[8],  (const float*)d_in[14], (const float*)d_in[20]};
    const float* Wg[3]   = {(const float*)d_in[9],  (const float*)d_in[15], (const float*)d_in[21]};
    const float* bg[3]   = {(const float*)d_in[10], (const float*)d_in[16], (const float*)d_in[22]};
    const float* Wc[3]   = {(const float*)d_in[11], (const float*)d_in[17], (const float*)d_in[23]};
    const float* bc[3]   = {(const float*)d_in[12], (const float*)d_in[18], (const float*)d_in[24]};

    const long HSZ  = (long)BATCH * HID * HH * WW;       // 2,097,152
    const long PSZ  = (long)BATCH * PROJ * HH * WW;      // 1,048,576
    const long GSZ  = (long)BATCH * 2 * HID * HH * WW;   // 4,194,304
    const long XSZ  = (long)BATCH * CIN_X * HH * WW;     //    98,304

    float* ws = (float*)d_ws;
    long off = 0;
    float* hbuf[6];
    for (int i = 0; i < 6; ++i) { hbuf[i] = ws + off; off += HSZ; }
    float* p     = ws + off; off += PSZ;
    float* bu    = ws + off; off += PSZ;
    float* gates = ws + off; off += GSZ;
    float* xzero = ws + off; off += XSZ;
    // repacked weights
    float* rWin0    = ws + off; off += (long)PROJ * CIN_X * 9;
    float* rWe10    = ws + off; off += (long)PROJ * HID * 9;
    float* rWe21    = ws + off; off += (long)PROJ * HID * 9;
    float* rWint[3]; for (int n = 0; n < 3; ++n) { rWint[n] = ws + off; off += (long)CDIM * PROJ * 9; }
    float* rWg[3];   for (int n = 0; n < 3; ++n) { rWg[n]   = ws + off; off += (long)2 * HID * (CDIM + HID) * 9; }
    float* rWc[3];   for (int n = 0; n < 3; ++n) { rWc[n]   = ws + off; off += (long)HID * (CDIM + HID) * 9; }
    (void)ws_size; (void)n_in; (void)in_sizes; (void)out_size;

    // init state + zero stimulus
    float* hc[3] = {hbuf[0], hbuf[1], hbuf[2]};
    float* hn[3] = {hbuf[3], hbuf[4], hbuf[5]};
    for (int n = 0; n < 3; ++n) hipMemsetAsync(hc[n], 0, HSZ * sizeof(float), stream);
    hipMemsetAsync(xzero, 0, XSZ * sizeof(float), stream);

    // repack all weights
    launch_repack(Win0, rWin0, PROJ, CIN_X, stream);
    launch_repack(We10, rWe10, PROJ, HID, stream);
    launch_repack(We21, rWe21, PROJ, HID, stream);
    for (int n = 0; n < 3; ++n) {
        launch_repack(Wint[n], rWint[n], CDIM, PROJ, stream);
        launch_repack(Wg[n],   rWg[n],   2 * HID, CDIM + HID, stream);
        launch_repack(Wc[n],   rWc[n],   HID, CDIM + HID, stream);
    }

    const long xBatchStride = (long)TSEQ * CIN_X * HH * WW;
    const long stdStrideH   = (long)HID * HH * WW;

    for (int t = 0; t < PT; ++t) {
        // ---- node 0 ----
        {
            const float* in0 = (t < TSEQ) ? (x + (long)t * CIN_X * HH * WW) : xzero;
            long aStr = (t < TSEQ) ? xBatchStride : (long)CIN_X * HH * WW;
            launch_conv(0, in0, CIN_X, aStr, nullptr, 0, nullptr, rWin0, bin0, p, PROJ, stream);
            launch_conv(0, p, PROJ, (long)PROJ * HH * WW, nullptr, 0, nullptr, rWint[0], bint[0], bu, CDIM, stream);
            launch_conv(1, bu, CDIM, (long)CDIM * HH * WW, hc[0], HID, nullptr, rWg[0], bg[0], gates, 2 * HID, stream);
            launch_conv(2, bu, CDIM, (long)CDIM * HH * WW, hc[0], HID, gates, rWc[0], bc[0], hn[0], HID, stream);
        }
        // ---- node 1 (reads PREVIOUS h0 = hc[0], not yet swapped) ----
        if (t >= 1) {
            launch_conv(0, hc[0], HID, stdStrideH, nullptr, 0, nullptr, rWe10, be10, p, PROJ, stream);
            launch_conv(0, p, PROJ, (long)PROJ * HH * WW, nullptr, 0, nullptr, rWint[1], bint[1], bu, CDIM, stream);
            launch_conv(1, bu, CDIM, (long)CDIM * HH * WW, hc[1], HID, nullptr, rWg[1], bg[1], gates, 2 * HID, stream);
            launch_conv(2, bu, CDIM, (long)CDIM * HH * WW, hc[1], HID, gates, rWc[1], bc[1], hn[1], HID, stream);
        }
        // ---- node 2 ----
        if (t >= 2) {
            launch_conv(0, hc[1], HID, stdStrideH, nullptr, 0, nullptr, rWe21, be21, p, PROJ, stream);
            launch_conv(0, p, PROJ, (long)PROJ * HH * WW, nullptr, 0, nullptr, rWint[2], bint[2], bu, CDIM, stream);
            launch_conv(1, bu, CDIM, (long)CDIM * HH * WW, hc[2], HID, nullptr, rWg[2], bg[2], gates, 2 * HID, stream);
            launch_conv(2, bu, CDIM, (long)CDIM * HH * WW, hc[2], HID, gates, rWc[2], bc[2], hn[2], HID, stream);
        }
        // wait: node-1/2 proj convs above read hc[0]/hc[1]; they were launched
        // BEFORE any swap, and node-0/1 updates write hn[0]/hn[1] (distinct
        // buffers), so ordering within the stream is correct. Now swap.
        { float* tmp = hc[0]; hc[0] = hn[0]; hn[0] = tmp; }
        if (t >= 1) { float* tmp = hc[1]; hc[1] = hn[1]; hn[1] = tmp; }
        if (t >= 2) { float* tmp = hc[2]; hc[2] = hn[2]; hn[2] = tmp; }
    }

    copy_k<<<((int)HSZ + 255) / 256, 256, 0, stream>>>(hc[2], (float*)d_out, (int)HSZ);
}

// Round 2
// 1319.115 us; speedup vs baseline: 9.1763x; 9.1763x over previous
//
#include <hip/hip_runtime.h>
#include <hip/hip_bf16.h>

#define BATCH 8
#define TSEQ 8
#define HH 64
#define WW 64
#define HID 64
#define PT 10   // T + NUM_NODE - 1

typedef __bf16 bf16_t;
typedef __bf16 bf16x8 __attribute__((ext_vector_type(8)));
typedef float  f32x4  __attribute__((ext_vector_type(4)));

// ---------------------------------------------------------------------------
// Weight pack: OIHW fp32 -> bf16 MFMA B-fragment stream:
//   wp[(((tap*(CinPad/32)+cic)*(Cout/16)+coc)*64 + lane)*8 + j]
//     = w[co = coc*16 + (lane&15)][ci = cic*32 + (lane>>4)*8 + j][tap]
// (zero-padded for ci >= CinReal)
// ---------------------------------------------------------------------------
__global__ void wpack_k(const float* __restrict__ w, bf16_t* __restrict__ wp,
                        int Cout, int CinPad, int CinReal) {
    int idx = blockIdx.x * 256 + threadIdx.x;
    int total = 9 * (CinPad / 32) * (Cout / 16) * 512;
    if (idx >= total) return;
    int j    = idx & 7;
    int lane = (idx >> 3) & 63;
    int rest = idx >> 9;
    int ncoc = Cout / 16;
    int coc  = rest % ncoc;
    int rest2 = rest / ncoc;
    int ncic = CinPad / 32;
    int cic  = rest2 % ncic;
    int tap  = rest2 / ncic;
    int co = coc * 16 + (lane & 15);
    int ci = cic * 32 + (lane >> 4) * 8 + j;
    float v = (ci < CinReal) ? w[((long)co * CinReal + ci) * 9 + tap] : 0.0f;
    wp[idx] = (bf16_t)v;
}

// x (B,T,3,H,W) fp32 -> xb [t][b][y][x][32] bf16 (channels 3..31 zero)
__global__ void xcvt_k(const float* __restrict__ x, bf16_t* __restrict__ xb) {
    int idx = blockIdx.x * 256 + threadIdx.x;   // 8*8*64*64*32 = 8388608
    if (idx >= 8 * 8 * 64 * 64 * 32) return;
    int c  = idx & 31;
    int xx = (idx >> 5) & 63;
    int y  = (idx >> 11) & 63;
    int b  = (idx >> 17) & 7;
    int t  = idx >> 20;
    float v = 0.0f;
    if (c < 3) v = x[((((long)b * TSEQ + t) * 3 + c) * 64 + y) * 64 + xx];
    xb[idx] = (bf16_t)v;
}

// h fp32 NHWC -> NCHW fp32 out
__global__ void hout_k(const float* __restrict__ hf, float* __restrict__ out) {
    int idx = blockIdx.x * 256 + threadIdx.x;   // b,c,y,x : 8*64*64*64
    if (idx >= 8 * 64 * 64 * 64) return;
    int xx = idx & 63;
    int y  = (idx >> 6) & 63;
    int c  = (idx >> 12) & 63;
    int b  = idx >> 18;
    out[idx] = hf[((((long)b * 64 + y) * 64 + xx) * 64) + c];
}

// ---------------------------------------------------------------------------
// MFMA implicit-GEMM 3x3 conv. One block per (b,y) row: M=64 px, N=COUT.
// Stages [3 rows][66 px][CIN] bf16 in LDS, XOR-swizzled (byte ^= (px&7)<<4).
// MODE 0: out bf16 NHWC.  MODE 1: sigmoid -> gates fp32 NHWC (2*HID ch).
// MODE 2: staging uses r*h for channels >= CIN0; epilogue GRU update,
//         writes h fp32 + h bf16.
// ---------------------------------------------------------------------------
template <int CIN0, int CIN1, int COUT, int MODE>
__global__ __launch_bounds__(256, 2) void mconv(
    const bf16_t* __restrict__ A0,
    const bf16_t* __restrict__ A1,
    const float*  __restrict__ Gf,      // gates fp32 (MODE2: r in staging, z in epilogue)
    const float*  __restrict__ Hf,      // old h fp32 (MODE2)
    const bf16_t* __restrict__ Wp,
    const float*  __restrict__ bias,
    bf16_t* __restrict__ outB,
    float*  __restrict__ outF)
{
    constexpr int CIN = CIN0 + CIN1;
    constexpr int NT  = COUT / 16;
    constexpr int NCH = CIN / 8;                 // 16B chunks per pixel

    const int tid  = threadIdx.x;
    const int lane = tid & 63;
    const int w    = tid >> 6;
    const int bid  = blockIdx.x;
    const int b = bid >> 6, y = bid & 63;

    __shared__ __align__(16) char smem[3 * 66 * CIN * 2];

    // ---- stage A ----
    const int totalChunks = 3 * 66 * NCH;
    for (int c = tid; c < totalChunks; c += 256) {
        int ry = c / (66 * NCH);
        int r  = c - ry * 66 * NCH;
        int px = r / NCH;
        int c2 = r - px * NCH;
        int gy = y + ry - 1, gx = px - 1;
        bf16x8 v = {};
        if ((unsigned)gy < (unsigned)HH && (unsigned)gx < (unsigned)WW) {
            long pix = ((long)b * HH + gy) * WW + gx;
            int ci = c2 * 8;
            if (CIN1 == 0 || ci < CIN0) {
                v = *(const bf16x8*)(A0 + pix * CIN0 + ci);
            } else {
                int ch = ci - CIN0;
                bf16x8 hv = *(const bf16x8*)(A1 + pix * CIN1 + ch);
                if (MODE == 2) {
                    const float* rp = Gf + pix * (2 * HID) + ch;
                    f32x4 r0 = *(const f32x4*)(rp);
                    f32x4 r1 = *(const f32x4*)(rp + 4);
#pragma unroll
                    for (int j = 0; j < 4; ++j) hv[j]     = (bf16_t)(r0[j] * (float)hv[j]);
#pragma unroll
                    for (int j = 0; j < 4; ++j) hv[4 + j] = (bf16_t)(r1[j] * (float)hv[4 + j]);
                }
                v = hv;
            }
        }
        int byte = ((ry * 66 + px) * CIN + c2 * 8) * 2;
        byte ^= (px & 7) << 4;
        *(bf16x8*)(smem + byte) = v;
    }
    __syncthreads();

    // ---- wave tiling ----
    constexpr int MT_N = (NT >= 4) ? 4 : 2;
    constexpr int NTW  = (NT >= 4) ? NT / 4 : 1;
    int mt0, nt0;
    if (NT >= 4) { mt0 = 0;            nt0 = w * NTW; }
    else         { mt0 = (w & 1) * 2;  nt0 = w >> 1;  }

    const int mrow = lane & 15;
    const int kgrp = lane >> 4;

    f32x4 acc[MT_N][NTW];
#pragma unroll
    for (int mi = 0; mi < MT_N; ++mi)
#pragma unroll
        for (int i = 0; i < NTW; ++i) {
            float bv = bias[(nt0 + i) * 16 + mrow];
            acc[mi][i] = (f32x4){bv, bv, bv, bv};
        }

    // ---- K loop: taps x ci-chunks ----
#pragma unroll
    for (int tap = 0; tap < 9; ++tap) {
        const int ky = tap / 3, kx = tap % 3;
#pragma unroll
        for (int cic = 0; cic < CIN / 32; ++cic) {
            bf16x8 bfrag[NTW];
#pragma unroll
            for (int i = 0; i < NTW; ++i)
                bfrag[i] = *(const bf16x8*)(Wp +
                    ((size_t)(((tap * (CIN / 32) + cic) * NT + (nt0 + i)) * 64 + lane)) * 8);
#pragma unroll
            for (int mi = 0; mi < MT_N; ++mi) {
                int px = (mt0 + mi) * 16 + mrow + kx;
                int byte = ((ky * 66 + px) * CIN + cic * 32 + kgrp * 8) * 2;
                byte ^= (px & 7) << 4;
                bf16x8 a = *(const bf16x8*)(smem + byte);
#pragma unroll
                for (int i = 0; i < NTW; ++i)
                    acc[mi][i] = __builtin_amdgcn_mfma_f32_16x16x32_bf16(
                        a, bfrag[i], acc[mi][i], 0, 0, 0);
            }
        }
    }

    // ---- epilogue ----
    const long rowPix = ((long)b * HH + y) * WW;
#pragma unroll
    for (int mi = 0; mi < MT_N; ++mi) {
#pragma unroll
        for (int i = 0; i < NTW; ++i) {
            int co = (nt0 + i) * 16 + mrow;
#pragma unroll
            for (int rg = 0; rg < 4; ++rg) {
                int xx = (mt0 + mi) * 16 + kgrp * 4 + rg;
                long pix = rowPix + xx;
                float v = acc[mi][i][rg];
                if (MODE == 0) {
                    outB[pix * COUT + co] = (bf16_t)v;
                } else if (MODE == 1) {
                    outF[pix * (2 * HID) + co] = 1.0f / (1.0f + expf(-v));
                } else {
                    float cd = tanhf(v);
                    float z  = Gf[pix * (2 * HID) + HID + co];
                    float ho = Hf[pix * HID + co];
                    float hn = z * ho + (1.0f - z) * cd;
                    outF[pix * HID + co] = hn;
                    outB[pix * HID + co] = (bf16_t)hn;
                }
            }
        }
    }
}

// ---------------------------------------------------------------------------
extern "C" void kernel_launch(void* const* d_in, const int* in_sizes, int n_in,
                              void* d_out, int out_size, void* d_ws, size_t ws_size,
                              hipStream_t stream) {
    const float* x    = (const float*)d_in[0];
    const float* Win0 = (const float*)d_in[1];
    const float* bin0 = (const float*)d_in[2];
    const float* We10 = (const float*)d_in[3];
    const float* be10 = (const float*)d_in[4];
    const float* We21 = (const float*)d_in[5];
    const float* be21 = (const float*)d_in[6];
    const float* Wint[3] = {(const float*)d_in[7],  (const float*)d_in[13], (const float*)d_in[19]};
    const float* bint[3] = {(const float*)d_in[8],  (const float*)d_in[14], (const float*)d_in[20]};
    const float* Wg[3]   = {(const float*)d_in[9],  (const float*)d_in[15], (const float*)d_in[21]};
    const float* bg[3]   = {(const float*)d_in[10], (const float*)d_in[16], (const float*)d_in[22]};
    const float* Wc[3]   = {(const float*)d_in[11], (const float*)d_in[17], (const float*)d_in[23]};
    const float* bc[3]   = {(const float*)d_in[12], (const float*)d_in[18], (const float*)d_in[24]};
    (void)in_sizes; (void)n_in; (void)out_size; (void)ws_size;

    const long PIX  = (long)BATCH * HH * WW;      // 32768
    char* wsb = (char*)d_ws;
    size_t off = 0;
    auto alloc = [&](size_t bytes) -> char* {
        char* p = wsb + off;
        off = (off + bytes + 255) & ~(size_t)255;
        return p;
    };

    bf16_t* xb    = (bf16_t*)alloc((size_t)TSEQ * PIX * 32 * 2);
    bf16_t* xzero = (bf16_t*)alloc((size_t)PIX * 32 * 2);
    bf16_t* p     = (bf16_t*)alloc((size_t)PIX * 32 * 2);
    bf16_t* bu    = (bf16_t*)alloc((size_t)PIX * 32 * 2);
    float*  gatesF = (float*)alloc((size_t)PIX * 2 * HID * 4);
    float*  hF[6];
    bf16_t* hB[6];
    for (int i = 0; i < 6; ++i) hF[i] = (float*) alloc((size_t)PIX * HID * 4);
    for (int i = 0; i < 6; ++i) hB[i] = (bf16_t*)alloc((size_t)PIX * HID * 2);
    bf16_t* WpIn0 = (bf16_t*)alloc((size_t)9 * 32 * 32 * 2);
    bf16_t* WpE10 = (bf16_t*)alloc((size_t)9 * 64 * 32 * 2);
    bf16_t* WpE21 = (bf16_t*)alloc((size_t)9 * 64 * 32 * 2);
    bf16_t* WpInt[3], *WpG[3], *WpC[3];
    for (int n = 0; n < 3; ++n) WpInt[n] = (bf16_t*)alloc((size_t)9 * 32 * 32 * 2);
    for (int n = 0; n < 3; ++n) WpG[n]   = (bf16_t*)alloc((size_t)9 * 96 * 128 * 2);
    for (int n = 0; n < 3; ++n) WpC[n]   = (bf16_t*)alloc((size_t)9 * 96 * 64 * 2);

    // ---- init ----
    for (int n = 0; n < 3; ++n) {
        hipMemsetAsync(hF[n], 0, (size_t)PIX * HID * 4, stream);
        hipMemsetAsync(hB[n], 0, (size_t)PIX * HID * 2, stream);
    }
    hipMemsetAsync(xzero, 0, (size_t)PIX * 32 * 2, stream);

    // ---- weight packing ----
    auto pack = [&](const float* w, bf16_t* wp, int Cout, int CinPad, int CinReal) {
        int total = 9 * (CinPad / 32) * (Cout / 16) * 512;
        wpack_k<<<(total + 255) / 256, 256, 0, stream>>>(w, wp, Cout, CinPad, CinReal);
    };
    pack(Win0, WpIn0, 32, 32, 3);
    pack(We10, WpE10, 32, 64, 64);
    pack(We21, WpE21, 32, 64, 64);
    for (int n = 0; n < 3; ++n) {
        pack(Wint[n], WpInt[n], 32, 32, 32);
        pack(Wg[n],   WpG[n],   128, 96, 96);
        pack(Wc[n],   WpC[n],   64, 96, 96);
    }
    xcvt_k<<<(8 * 8 * 64 * 64 * 32 + 255) / 256, 256, 0, stream>>>(x, xb);

    // ---- recurrence ----
    float*  hFc[3] = {hF[0], hF[1], hF[2]};
    float*  hFn[3] = {hF[3], hF[4], hF[5]};
    bf16_t* hBc[3] = {hB[0], hB[1], hB[2]};
    bf16_t* hBn[3] = {hB[3], hB[4], hB[5]};

    const dim3 G(BATCH * HH), T(256);
    const long XS = PIX * 32;

    for (int t = 0; t < PT; ++t) {
        // node 0
        {
            const bf16_t* xt = (t < TSEQ) ? (xb + (long)t * XS) : xzero;
            mconv<32, 0, 32, 0><<<G, T, 0, stream>>>(xt, nullptr, nullptr, nullptr, WpIn0, bin0, p, nullptr);
            mconv<32, 0, 32, 0><<<G, T, 0, stream>>>(p, nullptr, nullptr, nullptr, WpInt[0], bint[0], bu, nullptr);
            mconv<32, 64, 128, 1><<<G, T, 0, stream>>>(bu, hBc[0], nullptr, nullptr, WpG[0], bg[0], nullptr, gatesF);
            mconv<32, 64, 64, 2><<<G, T, 0, stream>>>(bu, hBc[0], gatesF, hFc[0], WpC[0], bc[0], hBn[0], hFn[0]);
        }
        // node 1 (reads pre-update hBc[0])
        if (t >= 1) {
            mconv<64, 0, 32, 0><<<G, T, 0, stream>>>(hBc[0], nullptr, nullptr, nullptr, WpE10, be10, p, nullptr);
            mconv<32, 0, 32, 0><<<G, T, 0, stream>>>(p, nullptr, nullptr, nullptr, WpInt[1], bint[1], bu, nullptr);
            mconv<32, 64, 128, 1><<<G, T, 0, stream>>>(bu, hBc[1], nullptr, nullptr, WpG[1], bg[1], nullptr, gatesF);
            mconv<32, 64, 64, 2><<<G, T, 0, stream>>>(bu, hBc[1], gatesF, hFc[1], WpC[1], bc[1], hBn[1], hFn[1]);
        }
        // node 2 (reads pre-update hBc[1])
        if (t >= 2) {
            mconv<64, 0, 32, 0><<<G, T, 0, stream>>>(hBc[1], nullptr, nullptr, nullptr, WpE21, be21, p, nullptr);
            mconv<32, 0, 32, 0><<<G, T, 0, stream>>>(p, nullptr, nullptr, nullptr, WpInt[2], bint[2], bu, nullptr);
            mconv<32, 64, 128, 1><<<G, T, 0, stream>>>(bu, hBc[2], nullptr, nullptr, WpG[2], bg[2], nullptr, gatesF);
            mconv<32, 64, 64, 2><<<G, T, 0, stream>>>(bu, hBc[2], gatesF, hFc[2], WpC[2], bc[2], hBn[2], hFn[2]);
        }
        // swap active nodes
        { float* tf = hFc[0]; hFc[0] = hFn[0]; hFn[0] = tf;
          bf16_t* tb = hBc[0]; hBc[0] = hBn[0]; hBn[0] = tb; }
        if (t >= 1) { float* tf = hFc[1]; hFc[1] = hFn[1]; hFn[1] = tf;
                      bf16_t* tb = hBc[1]; hBc[1] = hBn[1]; hBn[1] = tb; }
        if (t >= 2) { float* tf = hFc[2]; hFc[2] = hFn[2]; hFn[2] = tf;
                      bf16_t* tb = hBc[2]; hBc[2] = hBn[2]; hBn[2] = tb; }
    }

    hout_k<<<(8 * 64 * 64 * 64 + 255) / 256, 256, 0, stream>>>(hFc[2], (float*)d_out);
}

// Round 3
// 973.788 us; speedup vs baseline: 12.4305x; 1.3546x over previous
//
#include <hip/hip_runtime.h>
#include <hip/hip_bf16.h>

#define BATCH 8
#define TSEQ 8
#define HH 64
#define WW 64
#define HID 64
#define PT 10   // T + NUM_NODE - 1

typedef __bf16 bf16_t;
typedef __bf16 bf16x8 __attribute__((ext_vector_type(8)));
typedef float  f32x4  __attribute__((ext_vector_type(4)));

// ---------------------------------------------------------------------------
// All-weights pack: OIHW fp32 -> bf16 MFMA B-fragment stream per segment:
//   dst[(((tap*(CinPad/32)+cic)*(Cout/16)+coc)*64 + lane)*8 + j]
//     = w[co = coc*16 + (lane&15)][ci = cic*32 + (lane>>4)*8 + j][tap]
// ---------------------------------------------------------------------------
struct PackSeg { const float* src; bf16_t* dst; int Cout; int CinPad; int CinReal; int begin; };
struct PackArgs { PackSeg s[12]; int total; };

__global__ void wpack_all(PackArgs P) {
    int idx = blockIdx.x * 256 + threadIdx.x;
    if (idx >= P.total) return;
    int si = 0;
#pragma unroll
    for (int i = 1; i < 12; ++i) if (idx >= P.s[i].begin) si = i;
    PackSeg sg = P.s[si];
    int l = idx - sg.begin;
    int j    = l & 7;
    int lane = (l >> 3) & 63;
    int rest = l >> 9;
    int ncoc = sg.Cout >> 4;
    int coc  = rest % ncoc;
    int rest2 = rest / ncoc;
    int ncic = sg.CinPad >> 5;
    int cic  = rest2 % ncic;
    int tap  = rest2 / ncic;
    int co = coc * 16 + (lane & 15);
    int ci = cic * 32 + (lane >> 4) * 8 + j;
    float v = (ci < sg.CinReal) ? sg.src[((long)co * sg.CinReal + ci) * 9 + tap] : 0.0f;
    sg.dst[l] = (bf16_t)v;
}

// x (B,T,3,H,W) fp32 -> xb [t][b][y][x][32] bf16 (channels 3..31 zero)
__global__ void xcvt_k(const float* __restrict__ x, bf16_t* __restrict__ xb) {
    int idx = blockIdx.x * 256 + threadIdx.x;
    if (idx >= 8 * 8 * 64 * 64 * 32) return;
    int c  = idx & 31;
    int xx = (idx >> 5) & 63;
    int y  = (idx >> 11) & 63;
    int b  = (idx >> 17) & 7;
    int t  = idx >> 20;
    float v = 0.0f;
    if (c < 3) v = x[((((long)b * TSEQ + t) * 3 + c) * 64 + y) * 64 + xx];
    xb[idx] = (bf16_t)v;
}

// h fp32 NHWC -> NCHW fp32 out
__global__ void hout_k(const float* __restrict__ hf, float* __restrict__ out) {
    int idx = blockIdx.x * 256 + threadIdx.x;
    if (idx >= 8 * 64 * 64 * 64) return;
    int xx = idx & 63;
    int y  = (idx >> 6) & 63;
    int c  = (idx >> 12) & 63;
    int b  = idx >> 18;
    out[idx] = hf[((((long)b * 64 + y) * 64 + xx) * 64) + c];
}

// ---------------------------------------------------------------------------
// MFMA implicit-GEMM 3x3 conv; multi-node via blockIdx.y -> per-node pointers.
// MODE 0: plain conv, out bf16 NHWC.
// MODE 1: gates conv (Cout=128): sigmoid; co<64 -> rh bf16 (= r * Hb),
//         co>=64 -> z fp32.
// MODE 2: cand conv (Cout=64), A1 = rh; epilogue h_new = z*h + (1-z)*tanh,
//         writes h fp32 + h bf16.
// ---------------------------------------------------------------------------
struct NP {
    const bf16_t* A0;
    const bf16_t* A1;
    const float*  Zf;    // z fp32 (MODE2)
    const float*  Hf;    // old h fp32 (MODE2)
    const bf16_t* Hb;    // old h bf16 (MODE1: rh = sigmoid * Hb)
    const bf16_t* Wp;
    const float*  bias;
    bf16_t* outB;
    float*  outF;
};
struct NPs { NP n[3]; };

template <int CIN0, int CIN1, int COUT, int MODE>
__global__ __launch_bounds__(256, 2) void mconv(NPs P)
{
    constexpr int CIN = CIN0 + CIN1;
    constexpr int NT  = COUT / 16;
    constexpr int NCH = CIN / 8;

    const NP np = P.n[blockIdx.y];
    const int tid  = threadIdx.x;
    const int lane = tid & 63;
    const int w    = tid >> 6;
    const int bid  = blockIdx.x;
    const int b = bid >> 6, y = bid & 63;

    __shared__ __align__(16) char smem[3 * 66 * CIN * 2];

    // ---- stage A (concat A0|A1), XOR-swizzled ----
    const int totalChunks = 3 * 66 * NCH;
    for (int c = tid; c < totalChunks; c += 256) {
        int ry = c / (66 * NCH);
        int r  = c - ry * 66 * NCH;
        int px = r / NCH;
        int c2 = r - px * NCH;
        int gy = y + ry - 1, gx = px - 1;
        bf16x8 v = {};
        if ((unsigned)gy < (unsigned)HH && (unsigned)gx < (unsigned)WW) {
            long pix = ((long)b * HH + gy) * WW + gx;
            int ci = c2 * 8;
            if (CIN1 == 0 || ci < CIN0) {
                v = *(const bf16x8*)(np.A0 + pix * CIN0 + ci);
            } else {
                v = *(const bf16x8*)(np.A1 + pix * CIN1 + (ci - CIN0));
            }
        }
        int byte = ((ry * 66 + px) * CIN + c2 * 8) * 2;
        byte ^= (px & 7) << 4;
        *(bf16x8*)(smem + byte) = v;
    }
    __syncthreads();

    // ---- wave tiling ----
    constexpr int MT_N = (NT >= 4) ? 4 : 2;
    constexpr int NTW  = (NT >= 4) ? NT / 4 : 1;
    int mt0, nt0;
    if (NT >= 4) { mt0 = 0;            nt0 = w * NTW; }
    else         { mt0 = (w & 1) * 2;  nt0 = w >> 1;  }

    const int mrow = lane & 15;
    const int kgrp = lane >> 4;

    f32x4 acc[MT_N][NTW];
#pragma unroll
    for (int mi = 0; mi < MT_N; ++mi)
#pragma unroll
        for (int i = 0; i < NTW; ++i) {
            float bv = np.bias[(nt0 + i) * 16 + mrow];
            acc[mi][i] = (f32x4){bv, bv, bv, bv};
        }

    // ---- K loop: taps x ci-chunks ----
#pragma unroll
    for (int tap = 0; tap < 9; ++tap) {
        const int ky = tap / 3, kx = tap % 3;
#pragma unroll
        for (int cic = 0; cic < CIN / 32; ++cic) {
            bf16x8 bfrag[NTW];
#pragma unroll
            for (int i = 0; i < NTW; ++i)
                bfrag[i] = *(const bf16x8*)(np.Wp +
                    ((size_t)(((tap * (CIN / 32) + cic) * NT + (nt0 + i)) * 64 + lane)) * 8);
#pragma unroll
            for (int mi = 0; mi < MT_N; ++mi) {
                int px = (mt0 + mi) * 16 + mrow + kx;
                int byte = ((ky * 66 + px) * CIN + cic * 32 + kgrp * 8) * 2;
                byte ^= (px & 7) << 4;
                bf16x8 a = *(const bf16x8*)(smem + byte);
#pragma unroll
                for (int i = 0; i < NTW; ++i)
                    acc[mi][i] = __builtin_amdgcn_mfma_f32_16x16x32_bf16(
                        a, bfrag[i], acc[mi][i], 0, 0, 0);
            }
        }
    }

    // ---- epilogue ----
    const long rowPix = ((long)b * HH + y) * WW;
#pragma unroll
    for (int mi = 0; mi < MT_N; ++mi) {
#pragma unroll
        for (int i = 0; i < NTW; ++i) {
            int co = (nt0 + i) * 16 + mrow;
#pragma unroll
            for (int rg = 0; rg < 4; ++rg) {
                int xx = (mt0 + mi) * 16 + kgrp * 4 + rg;
                long pix = rowPix + xx;
                float v = acc[mi][i][rg];
                if (MODE == 0) {
                    np.outB[pix * COUT + co] = (bf16_t)v;
                } else if (MODE == 1) {
                    float s = 1.0f / (1.0f + expf(-v));
                    if (co < HID) {
                        float hv = (float)np.Hb[pix * HID + co];
                        np.outB[pix * HID + co] = (bf16_t)(s * hv);   // rh
                    } else {
                        np.outF[pix * HID + (co - HID)] = s;          // z
                    }
                } else {
                    float cd = tanhf(v);
                    float z  = np.Zf[pix * HID + co];
                    float ho = np.Hf[pix * HID + co];
                    float hn = z * ho + (1.0f - z) * cd;
                    np.outF[pix * HID + co] = hn;
                    np.outB[pix * HID + co] = (bf16_t)hn;
                }
            }
        }
    }
}

// ---------------------------------------------------------------------------
extern "C" void kernel_launch(void* const* d_in, const int* in_sizes, int n_in,
                              void* d_out, int out_size, void* d_ws, size_t ws_size,
                              hipStream_t stream) {
    const float* x    = (const float*)d_in[0];
    const float* Win0 = (const float*)d_in[1];
    const float* bin0 = (const float*)d_in[2];
    const float* We10 = (const float*)d_in[3];
    const float* be10 = (const float*)d_in[4];
    const float* We21 = (const float*)d_in[5];
    const float* be21 = (const float*)d_in[6];
    const float* Wint[3] = {(const float*)d_in[7],  (const float*)d_in[13], (const float*)d_in[19]};
    const float* bint[3] = {(const float*)d_in[8],  (const float*)d_in[14], (const float*)d_in[20]};
    const float* Wg[3]   = {(const float*)d_in[9],  (const float*)d_in[15], (const float*)d_in[21]};
    const float* bg[3]   = {(const float*)d_in[10], (const float*)d_in[16], (const float*)d_in[22]};
    const float* Wc[3]   = {(const float*)d_in[11], (const float*)d_in[17], (const float*)d_in[23]};
    const float* bc[3]   = {(const float*)d_in[12], (const float*)d_in[18], (const float*)d_in[24]};
    (void)in_sizes; (void)n_in; (void)out_size; (void)ws_size;

    const long PIX  = (long)BATCH * HH * WW;      // 32768
    const size_t HFSZ = (size_t)PIX * HID * 4;    // 8 MB
    const size_t HBSZ = (size_t)PIX * HID * 2;    // 4 MB
    const size_t XZSZ = (size_t)PIX * 32 * 2;     // 2 MB
    const long PSZ  = PIX * 32;                   // elems (bf16)
    const long RHSZ = PIX * HID;                  // elems (bf16)
    const long ZSZ  = PIX * HID;                  // elems (f32)

    char* wsb = (char*)d_ws;
    size_t off = 0;
    auto alloc = [&](size_t bytes) -> char* {
        char* q = wsb + off;
        off = (off + bytes + 255) & ~(size_t)255;
        return q;
    };

    // zero-group (must stay contiguous: all sizes are multiples of 256)
    float*  hF[6]; bf16_t* hB[6];
    hF[0] = (float*)alloc(HFSZ); hF[1] = (float*)alloc(HFSZ); hF[2] = (float*)alloc(HFSZ);
    hB[0] = (bf16_t*)alloc(HBSZ); hB[1] = (bf16_t*)alloc(HBSZ); hB[2] = (bf16_t*)alloc(HBSZ);
    bf16_t* xzero = (bf16_t*)alloc(XZSZ);
    const size_t zeroBytes = 3 * HFSZ + 3 * HBSZ + XZSZ;
    // rest
    hF[3] = (float*)alloc(HFSZ); hF[4] = (float*)alloc(HFSZ); hF[5] = (float*)alloc(HFSZ);
    hB[3] = (bf16_t*)alloc(HBSZ); hB[4] = (bf16_t*)alloc(HBSZ); hB[5] = (bf16_t*)alloc(HBSZ);
    bf16_t* xb = (bf16_t*)alloc((size_t)TSEQ * PIX * 32 * 2);
    bf16_t* p  = (bf16_t*)alloc((size_t)3 * PSZ * 2);
    bf16_t* bu = (bf16_t*)alloc((size_t)3 * PSZ * 2);
    bf16_t* rh = (bf16_t*)alloc((size_t)3 * RHSZ * 2);
    float*  zb = (float*) alloc((size_t)3 * ZSZ * 4);
    bf16_t* WpIn0 = (bf16_t*)alloc((size_t)9216 * 2);
    bf16_t* WpE10 = (bf16_t*)alloc((size_t)18432 * 2);
    bf16_t* WpE21 = (bf16_t*)alloc((size_t)18432 * 2);
    bf16_t* WpInt[3], *WpG[3], *WpC[3];
    for (int n = 0; n < 3; ++n) WpInt[n] = (bf16_t*)alloc((size_t)9216 * 2);
    for (int n = 0; n < 3; ++n) WpG[n]   = (bf16_t*)alloc((size_t)110592 * 2);
    for (int n = 0; n < 3; ++n) WpC[n]   = (bf16_t*)alloc((size_t)55296 * 2);

    // ---- init: one memset over the contiguous zero-group ----
    hipMemsetAsync(hF[0], 0, zeroBytes, stream);

    // ---- weight packing: single kernel ----
    PackArgs PA{};
    int beg = 0;
    auto seg = [&](int i, const float* src, bf16_t* dst, int Cout, int CinPad, int CinReal) {
        PA.s[i] = {src, dst, Cout, CinPad, CinReal, beg};
        beg += 9 * (CinPad / 32) * (Cout / 16) * 512;
    };
    seg(0, Win0, WpIn0, 32, 32, 3);
    seg(1, We10, WpE10, 32, 64, 64);
    seg(2, We21, WpE21, 32, 64, 64);
    for (int n = 0; n < 3; ++n) seg(3 + n, Wint[n], WpInt[n], 32, 32, 32);
    for (int n = 0; n < 3; ++n) seg(6 + n, Wg[n],   WpG[n],   128, 96, 96);
    for (int n = 0; n < 3; ++n) seg(9 + n, Wc[n],   WpC[n],   64, 96, 96);
    PA.total = beg;
    wpack_all<<<(PA.total + 255) / 256, 256, 0, stream>>>(PA);
    xcvt_k<<<(8 * 8 * 64 * 64 * 32 + 255) / 256, 256, 0, stream>>>(x, xb);

    // ---- recurrence ----
    float*  hFc[3] = {hF[0], hF[1], hF[2]};
    float*  hFn[3] = {hF[3], hF[4], hF[5]};
    bf16_t* hBc[3] = {hB[0], hB[1], hB[2]};
    bf16_t* hBn[3] = {hB[3], hB[4], hB[5]};
    const bf16_t* WpE[2]  = {WpE10, WpE21};
    const float*  beE[2]  = {be10, be21};

    const dim3 T(256);
    for (int t = 0; t < PT; ++t) {
        const int nAct = (t + 1 < 3) ? (t + 1) : 3;
        // proj node0 (x path, CIN=32)
        {
            NPs P{};
            P.n[0].A0 = (t < TSEQ) ? (xb + (long)t * PIX * 32) : xzero;
            P.n[0].Wp = WpIn0; P.n[0].bias = bin0; P.n[0].outB = p;
            mconv<32, 0, 32, 0><<<dim3(BATCH * HH, 1), T, 0, stream>>>(P);
        }
        // proj nodes 1..nAct-1 (h path, CIN=64)
        if (nAct > 1) {
            NPs P{};
            for (int n = 1; n < nAct; ++n) {
                P.n[n - 1].A0 = hBc[n - 1];
                P.n[n - 1].Wp = WpE[n - 1]; P.n[n - 1].bias = beE[n - 1];
                P.n[n - 1].outB = p + (long)n * PSZ;
            }
            mconv<64, 0, 32, 0><<<dim3(BATCH * HH, nAct - 1), T, 0, stream>>>(P);
        }
        // integrator (all active nodes)
        {
            NPs P{};
            for (int n = 0; n < nAct; ++n) {
                P.n[n].A0 = p + (long)n * PSZ;
                P.n[n].Wp = WpInt[n]; P.n[n].bias = bint[n];
                P.n[n].outB = bu + (long)n * PSZ;
            }
            mconv<32, 0, 32, 0><<<dim3(BATCH * HH, nAct), T, 0, stream>>>(P);
        }
        // gates (writes rh bf16 + z fp32)
        {
            NPs P{};
            for (int n = 0; n < nAct; ++n) {
                P.n[n].A0 = bu + (long)n * PSZ; P.n[n].A1 = hBc[n]; P.n[n].Hb = hBc[n];
                P.n[n].Wp = WpG[n]; P.n[n].bias = bg[n];
                P.n[n].outB = rh + (long)n * RHSZ; P.n[n].outF = zb + (long)n * ZSZ;
            }
            mconv<32, 64, 128, 1><<<dim3(BATCH * HH, nAct), T, 0, stream>>>(P);
        }
        // cand + GRU update
        {
            NPs P{};
            for (int n = 0; n < nAct; ++n) {
                P.n[n].A0 = bu + (long)n * PSZ; P.n[n].A1 = rh + (long)n * RHSZ;
                P.n[n].Zf = zb + (long)n * ZSZ; P.n[n].Hf = hFc[n];
                P.n[n].Wp = WpC[n]; P.n[n].bias = bc[n];
                P.n[n].outB = hBn[n]; P.n[n].outF = hFn[n];
            }
            mconv<32, 64, 64, 2><<<dim3(BATCH * HH, nAct), T, 0, stream>>>(P);
        }
        // swap active nodes
        for (int n = 0; n < nAct; ++n) {
            float* tf = hFc[n]; hFc[n] = hFn[n]; hFn[n] = tf;
            bf16_t* tb = hBc[n]; hBc[n] = hBn[n]; hBn[n] = tb;
        }
    }

    hout_k<<<(8 * 64 * 64 * 64 + 255) / 256, 256, 0, stream>>>(hFc[2], (float*)d_out);
}

// Round 4
// 893.394 us; speedup vs baseline: 13.5490x; 1.0900x over previous
//
#include <hip/hip_runtime.h>
#include <hip/hip_bf16.h>

#define BATCH 8
#define TSEQ 8
#define HH 64
#define WW 64
#define HID 64
#define PT 10   // T + NUM_NODE - 1

typedef __bf16 bf16_t;
typedef __bf16 bf16x8 __attribute__((ext_vector_type(8)));
typedef float  f32x16 __attribute__((ext_vector_type(16)));

// fast transcendentals (v_exp_f32 + v_rcp_f32)
__device__ __forceinline__ float fsigmoid(float v) {
    float e = __builtin_amdgcn_exp2f(-1.4426950408889634f * v);
    return __builtin_amdgcn_rcpf(1.0f + e);
}
__device__ __forceinline__ float ftanh(float v) {
    float e = __builtin_amdgcn_exp2f(2.8853900817779268f * v);   // e^(2v)
    return 1.0f - 2.0f * __builtin_amdgcn_rcpf(1.0f + e);
}

// ---------------------------------------------------------------------------
// Weight pack for 32x32x16 MFMA B-fragments:
//   dst[((chunk*NT32 + nt)*64 + lane)*8 + j],  chunk = tap*KC + kc
//     = w[co = nt*32 + (lane&31)][ci = kc*16 + (lane>>5)*8 + j][tap]
// ---------------------------------------------------------------------------
struct PackSeg { const float* src; bf16_t* dst; int NT32; int KC; int CinReal; int begin; };
struct PackArgs { PackSeg s[12]; int total; };

__global__ void wpack_all(PackArgs P) {
    int idx = blockIdx.x * 256 + threadIdx.x;
    if (idx >= P.total) return;
    int si = 0;
#pragma unroll
    for (int i = 1; i < 12; ++i) if (idx >= P.s[i].begin) si = i;
    PackSeg sg = P.s[si];
    int l = idx - sg.begin;
    int j    = l & 7;
    int lane = (l >> 3) & 63;
    int rest = l >> 9;
    int nt   = rest % sg.NT32;
    int chunk = rest / sg.NT32;
    int kc  = chunk % sg.KC;
    int tap = chunk / sg.KC;
    int co = nt * 32 + (lane & 31);
    int ci = kc * 16 + (lane >> 5) * 8 + j;
    float v = (ci < sg.CinReal) ? sg.src[((long)co * sg.CinReal + ci) * 9 + tap] : 0.0f;
    sg.dst[l] = (bf16_t)v;
}

// x (B,T,3,H,W) fp32 -> xb [t][b][y][x][64] bf16 (channels 3..63 zero)
__global__ void xcvt_k(const float* __restrict__ x, bf16_t* __restrict__ xb) {
    int idx = blockIdx.x * 256 + threadIdx.x;
    if (idx >= 8 * 8 * 64 * 64 * 64) return;
    int c  = idx & 63;
    int xx = (idx >> 6) & 63;
    int y  = (idx >> 12) & 63;
    int b  = (idx >> 18) & 7;
    int t  = idx >> 21;
    float v = 0.0f;
    if (c < 3) v = x[((((long)b * TSEQ + t) * 3 + c) * 64 + y) * 64 + xx];
    xb[idx] = (bf16_t)v;
}

// h fp32 NHWC -> NCHW fp32 out
__global__ void hout_k(const float* __restrict__ hf, float* __restrict__ out) {
    int idx = blockIdx.x * 256 + threadIdx.x;
    if (idx >= 8 * 64 * 64 * 64) return;
    int xx = idx & 63;
    int y  = (idx >> 6) & 63;
    int c  = (idx >> 12) & 63;
    int b  = idx >> 18;
    out[idx] = hf[((((long)b * 64 + y) * 64 + xx) * 64) + c];
}

// ---------------------------------------------------------------------------
// MFMA 32x32x16 implicit-GEMM 3x3 conv, ROWS=2 per block (M = 128 px).
// blockIdx.x: b = &7 (XCD-pinned), ychunk = >>3. blockIdx.y: node.
// MODE 0: plain conv, out bf16 NHWC.
// MODE 1: gates (COUT=128): sigmoid; co<64 -> rh bf16 (= r * Hb), co>=64 -> z fp32.
// MODE 2: cand (COUT=64): h_new = z*h + (1-z)*tanh; writes h fp32 + h bf16.
// ---------------------------------------------------------------------------
struct NP {
    const bf16_t* A0;
    const bf16_t* A1;
    const float*  Zf;
    const float*  Hf;
    const bf16_t* Hb;
    const bf16_t* Wp;
    const float*  bias;
    bf16_t* outB;
    float*  outF;
};
struct NPs { NP n[3]; };

template <int CIN0, int CIN1, int COUT, int MODE, int MINW>
__global__ __launch_bounds__(256, MINW) void mconv(NPs P)
{
    constexpr int CIN  = CIN0 + CIN1;
    constexpr int NT32 = COUT / 32;
    constexpr int NCH  = CIN / 8;
    constexpr int KC   = CIN / 16;
    constexpr int MT_W = (NT32 == 1) ? 1 : 2;   // M tiles per wave
    constexpr int NT_W = (NT32 == 4) ? 2 : 1;   // N tiles per wave

    const NP np   = P.n[blockIdx.y];
    const int tid  = threadIdx.x;
    const int lane = tid & 63;
    const int w    = tid >> 6;
    const int b  = blockIdx.x & 7;            // image -> XCD pinning
    const int y0 = (blockIdx.x >> 3) * 2;

    __shared__ __align__(16) char smem[4 * 66 * CIN * 2];

    // ---- stage 4 rows x 66 px x CIN (XOR-swizzled) ----
    for (int c = tid; c < 4 * 66 * NCH; c += 256) {
        int ry = c / (66 * NCH);
        int r  = c - ry * 66 * NCH;
        int px = r / NCH;
        int c2 = r - px * NCH;
        int gy = y0 + ry - 1, gx = px - 1;
        bf16x8 v = {};
        if ((unsigned)gy < 64u && (unsigned)gx < 64u) {
            long pix = ((long)b * 64 + gy) * 64 + gx;
            int ci = c2 * 8;
            if (CIN1 == 0 || ci < CIN0) v = *(const bf16x8*)(np.A0 + pix * CIN0 + ci);
            else                        v = *(const bf16x8*)(np.A1 + pix * CIN1 + (ci - CIN0));
        }
        int byte = ((ry * 66 + px) * CIN + c2 * 8) * 2;
        byte ^= (px & 7) << 4;
        *(bf16x8*)(smem + byte) = v;
    }
    __syncthreads();

    // ---- wave tile assignment ----
    int mt0, nt0;
    if (NT32 == 4)      { mt0 = (w >> 1) * 2; nt0 = (w & 1) * 2; }
    else if (NT32 == 2) { mt0 = (w >> 1) * 2; nt0 = (w & 1);     }
    else                { mt0 = w;            nt0 = 0;           }

    const int lm = lane & 31;
    const int kg = lane >> 5;

    f32x16 acc[MT_W][NT_W];
#pragma unroll
    for (int mi = 0; mi < MT_W; ++mi)
#pragma unroll
        for (int ni = 0; ni < NT_W; ++ni) {
            float bv = np.bias[(nt0 + ni) * 32 + lm];
#pragma unroll
            for (int r = 0; r < 16; ++r) acc[mi][ni][r] = bv;
        }

    // ---- K loop: 9 taps x KC chunks of K=16 ----
#pragma unroll
    for (int tap = 0; tap < 9; ++tap) {
        const int ky = tap / 3, kx = tap % 3;
#pragma unroll
        for (int kc = 0; kc < KC; ++kc) {
            bf16x8 bfrag[NT_W];
#pragma unroll
            for (int ni = 0; ni < NT_W; ++ni)
                bfrag[ni] = *(const bf16x8*)(np.Wp +
                    ((size_t)((tap * KC + kc) * NT32 + nt0 + ni) * 64 + lane) * 8);
#pragma unroll
            for (int mi = 0; mi < MT_W; ++mi) {
                int mt = mt0 + mi;
                int x  = (mt & 1) * 32 + lm + kx;
                int ry = (mt >> 1) + ky;
                int byte = ((ry * 66 + x) * CIN + kc * 16 + kg * 8) * 2;
                byte ^= (x & 7) << 4;
                bf16x8 a = *(const bf16x8*)(smem + byte);
#pragma unroll
                for (int ni = 0; ni < NT_W; ++ni)
                    acc[mi][ni] = __builtin_amdgcn_mfma_f32_32x32x16_bf16(
                        a, bfrag[ni], acc[mi][ni], 0, 0, 0);
            }
        }
    }

    // ---- epilogue ----
#pragma unroll
    for (int mi = 0; mi < MT_W; ++mi) {
        int mt = mt0 + mi;
        int oy = y0 + (mt >> 1);
        int xb0 = (mt & 1) * 32;
#pragma unroll
        for (int ni = 0; ni < NT_W; ++ni) {
            int co = (nt0 + ni) * 32 + lm;
#pragma unroll
            for (int reg = 0; reg < 16; ++reg) {
                int pxl = (reg & 3) + 8 * (reg >> 2) + 4 * kg;
                long pix = ((long)b * 64 + oy) * 64 + xb0 + pxl;
                float v = acc[mi][ni][reg];
                if (MODE == 0) {
                    np.outB[pix * COUT + co] = (bf16_t)v;
                } else if (MODE == 1) {
                    float s = fsigmoid(v);
                    if (co < HID) {
                        float hv = (float)np.Hb[pix * HID + co];
                        np.outB[pix * HID + co] = (bf16_t)(s * hv);   // rh
                    } else {
                        np.outF[pix * HID + (co - HID)] = s;          // z
                    }
                } else {
                    float cd = ftanh(v);
                    float z  = np.Zf[pix * HID + co];
                    float ho = np.Hf[pix * HID + co];
                    float hn = z * ho + (1.0f - z) * cd;
                    np.outF[pix * HID + co] = hn;
                    np.outB[pix * HID + co] = (bf16_t)hn;
                }
            }
        }
    }
}

// ---------------------------------------------------------------------------
extern "C" void kernel_launch(void* const* d_in, const int* in_sizes, int n_in,
                              void* d_out, int out_size, void* d_ws, size_t ws_size,
                              hipStream_t stream) {
    const float* x    = (const float*)d_in[0];
    const float* Win0 = (const float*)d_in[1];
    const float* bin0 = (const float*)d_in[2];
    const float* We10 = (const float*)d_in[3];
    const float* be10 = (const float*)d_in[4];
    const float* We21 = (const float*)d_in[5];
    const float* be21 = (const float*)d_in[6];
    const float* Wint[3] = {(const float*)d_in[7],  (const float*)d_in[13], (const float*)d_in[19]};
    const float* bint[3] = {(const float*)d_in[8],  (const float*)d_in[14], (const float*)d_in[20]};
    const float* Wg[3]   = {(const float*)d_in[9],  (const float*)d_in[15], (const float*)d_in[21]};
    const float* bg[3]   = {(const float*)d_in[10], (const float*)d_in[16], (const float*)d_in[22]};
    const float* Wc[3]   = {(const float*)d_in[11], (const float*)d_in[17], (const float*)d_in[23]};
    const float* bc[3]   = {(const float*)d_in[12], (const float*)d_in[18], (const float*)d_in[24]};
    (void)in_sizes; (void)n_in; (void)out_size; (void)ws_size;

    const long PIX  = (long)BATCH * HH * WW;      // 32768
    const size_t HFSZ = (size_t)PIX * HID * 4;    // 8 MB
    const size_t HBSZ = (size_t)PIX * HID * 2;    // 4 MB
    const size_t XZSZ = (size_t)PIX * 64 * 2;     // 4 MB
    const long PSZ  = PIX * 32;                   // bf16 elems
    const long RHSZ = PIX * HID;
    const long ZSZ  = PIX * HID;

    char* wsb = (char*)d_ws;
    size_t off = 0;
    auto alloc = [&](size_t bytes) -> char* {
        char* q = wsb + off;
        off = (off + bytes + 255) & ~(size_t)255;
        return q;
    };

    // zero-group (contiguous)
    float*  hF[6]; bf16_t* hB[6];
    hF[0] = (float*)alloc(HFSZ); hF[1] = (float*)alloc(HFSZ); hF[2] = (float*)alloc(HFSZ);
    hB[0] = (bf16_t*)alloc(HBSZ); hB[1] = (bf16_t*)alloc(HBSZ); hB[2] = (bf16_t*)alloc(HBSZ);
    bf16_t* xzero = (bf16_t*)alloc(XZSZ);
    const size_t zeroBytes = 3 * HFSZ + 3 * HBSZ + XZSZ;
    // rest
    hF[3] = (float*)alloc(HFSZ); hF[4] = (float*)alloc(HFSZ); hF[5] = (float*)alloc(HFSZ);
    hB[3] = (bf16_t*)alloc(HBSZ); hB[4] = (bf16_t*)alloc(HBSZ); hB[5] = (bf16_t*)alloc(HBSZ);
    bf16_t* xb = (bf16_t*)alloc((size_t)TSEQ * PIX * 64 * 2);
    bf16_t* p  = (bf16_t*)alloc((size_t)3 * PSZ * 2);
    bf16_t* bu = (bf16_t*)alloc((size_t)3 * PSZ * 2);
    bf16_t* rh = (bf16_t*)alloc((size_t)3 * RHSZ * 2);
    float*  zb = (float*) alloc((size_t)3 * ZSZ * 4);
    bf16_t* WpIn0 = (bf16_t*)alloc((size_t)18432 * 2);  // 9*4*1*512
    bf16_t* WpE10 = (bf16_t*)alloc((size_t)18432 * 2);
    bf16_t* WpE21 = (bf16_t*)alloc((size_t)18432 * 2);
    bf16_t* WpInt[3], *WpG[3], *WpC[3];
    for (int n = 0; n < 3; ++n) WpInt[n] = (bf16_t*)alloc((size_t)9216 * 2);   // 9*2*1*512
    for (int n = 0; n < 3; ++n) WpG[n]   = (bf16_t*)alloc((size_t)110592 * 2); // 9*6*4*512
    for (int n = 0; n < 3; ++n) WpC[n]   = (bf16_t*)alloc((size_t)55296 * 2);  // 9*6*2*512

    hipMemsetAsync(hF[0], 0, zeroBytes, stream);

    // ---- weight packing (one dispatch) ----
    PackArgs PA{};
    int beg = 0;
    auto seg = [&](int i, const float* src, bf16_t* dst, int Cout, int CinPad, int CinReal) {
        PA.s[i] = {src, dst, Cout / 32, CinPad / 16, CinReal, beg};
        beg += 9 * (CinPad / 16) * (Cout / 32) * 512;
    };
    seg(0, Win0, WpIn0, 32, 64, 3);
    seg(1, We10, WpE10, 32, 64, 64);
    seg(2, We21, WpE21, 32, 64, 64);
    for (int n = 0; n < 3; ++n) seg(3 + n, Wint[n], WpInt[n], 32, 32, 32);
    for (int n = 0; n < 3; ++n) seg(6 + n, Wg[n],   WpG[n],   128, 96, 96);
    for (int n = 0; n < 3; ++n) seg(9 + n, Wc[n],   WpC[n],   64, 96, 96);
    PA.total = beg;
    wpack_all<<<(PA.total + 255) / 256, 256, 0, stream>>>(PA);
    xcvt_k<<<(8 * 8 * 64 * 64 * 64 + 255) / 256, 256, 0, stream>>>(x, xb);

    // ---- recurrence ----
    float*  hFc[3] = {hF[0], hF[1], hF[2]};
    float*  hFn[3] = {hF[3], hF[4], hF[5]};
    bf16_t* hBc[3] = {hB[0], hB[1], hB[2]};
    bf16_t* hBn[3] = {hB[3], hB[4], hB[5]};
    const bf16_t* WpE[2] = {WpE10, WpE21};
    const float*  beE[2] = {be10, be21};

    const dim3 T(256);
    const int GX = BATCH * (HH / 2);   // 256 blocks

    for (int t = 0; t < PT; ++t) {
        const int nAct = (t + 1 < 3) ? (t + 1) : 3;
        // proj: all active nodes in one dispatch (CIN=64)
        {
            NPs P{};
            P.n[0].A0 = (t < TSEQ) ? (xb + (long)t * PIX * 64) : xzero;
            P.n[0].Wp = WpIn0; P.n[0].bias = bin0; P.n[0].outB = p;
            for (int n = 1; n < nAct; ++n) {
                P.n[n].A0 = hBc[n - 1];
                P.n[n].Wp = WpE[n - 1]; P.n[n].bias = beE[n - 1];
                P.n[n].outB = p + (long)n * PSZ;
            }
            mconv<64, 0, 32, 0, 4><<<dim3(GX, nAct), T, 0, stream>>>(P);
        }
        // integrator
        {
            NPs P{};
            for (int n = 0; n < nAct; ++n) {
                P.n[n].A0 = p + (long)n * PSZ;
                P.n[n].Wp = WpInt[n]; P.n[n].bias = bint[n];
                P.n[n].outB = bu + (long)n * PSZ;
            }
            mconv<32, 0, 32, 0, 4><<<dim3(GX, nAct), T, 0, stream>>>(P);
        }
        // gates (rh bf16 + z fp32)
        {
            NPs P{};
            for (int n = 0; n < nAct; ++n) {
                P.n[n].A0 = bu + (long)n * PSZ; P.n[n].A1 = hBc[n]; P.n[n].Hb = hBc[n];
                P.n[n].Wp = WpG[n]; P.n[n].bias = bg[n];
                P.n[n].outB = rh + (long)n * RHSZ; P.n[n].outF = zb + (long)n * ZSZ;
            }
            mconv<32, 64, 128, 1, 3><<<dim3(GX, nAct), T, 0, stream>>>(P);
        }
        // cand + GRU update
        {
            NPs P{};
            for (int n = 0; n < nAct; ++n) {
                P.n[n].A0 = bu + (long)n * PSZ; P.n[n].A1 = rh + (long)n * RHSZ;
                P.n[n].Zf = zb + (long)n * ZSZ; P.n[n].Hf = hFc[n];
                P.n[n].Wp = WpC[n]; P.n[n].bias = bc[n];
                P.n[n].outB = hBn[n]; P.n[n].outF = hFn[n];
            }
            mconv<32, 64, 64, 2, 3><<<dim3(GX, nAct), T, 0, stream>>>(P);
        }
        for (int n = 0; n < nAct; ++n) {
            float* tf = hFc[n]; hFc[n] = hFn[n]; hFn[n] = tf;
            bf16_t* tb = hBc[n]; hBc[n] = hBn[n]; hBn[n] = tb;
        }
    }

    hout_k<<<(8 * 64 * 64 * 64 + 255) / 256, 256, 0, stream>>>(hFc[2], (float*)d_out);
}